// Round 1
// baseline (211.683 us; speedup 1.0000x reference)
//
#include <hip/hip_runtime.h>
#include <stdint.h>

#define N_ANCHORS 6144
#define NUM_CLASSES 80
#define NWORDS 96   // 6144 / 64

// ---------------- static device scratch (avoids ws_size assumptions) ----------------
__device__ unsigned long long g_mask[(size_t)N_ANCHORS * NWORDS]; // suppression bitmask rows (sorted space)
__device__ float4 g_boxes[N_ANCHORS];    // per-anchor box
__device__ float4 g_sbox[N_ANCHORS];     // sorted boxes
__device__ float  g_key[N_ANCHORS];      // score if valid else -1
__device__ int    g_rank[N_ANCHORS];     // sorted position of valid anchor
__device__ int    g_fic[N_ANCHORS];      // filtered index of valid anchor
__device__ int    g_sAnchor[N_ANCHORS];  // sorted pos -> anchor id
__device__ int    g_sFi[N_ANCHORS];      // sorted pos -> filtered index
__device__ int    g_keptPos[N_ANCHORS];  // compact kept list (sorted positions, ascending)
__device__ int    g_F, g_K, g_np, g_done;
__device__ float  g_loss;

__device__ __forceinline__ unsigned long long shfl64(unsigned long long v, int l) {
    return __shfl(v, l, 64);
}

// ---------------- K1: per-anchor prep (fused zeroing; g_F counted in k_scatter to
// avoid zero/accumulate race within this kernel) ----------------
__global__ void k_prep(const float* __restrict__ loc, const float* __restrict__ conf,
                       const float* __restrict__ tb) {
    int i = blockIdx.x * 256 + threadIdx.x;
    if (i >= N_ANCHORS) return;
    g_rank[i] = 0; g_fic[i] = 0;
    if (i == 0) { g_F = 0; g_K = 0; g_np = 0; g_loss = 0.0f; g_done = 0; }
    const float4* cp4 = (const float4*)(conf + (size_t)i * NUM_CLASSES);
    float4 v0 = cp4[0];
    float score = v0.x;
    float m = fmaxf(fmaxf(v0.x, v0.y), fmaxf(v0.z, v0.w));
    #pragma unroll
    for (int c = 1; c < NUM_CLASSES / 4; ++c) {
        float4 v = cp4[c];
        m = fmaxf(m, fmaxf(fmaxf(v.x, v.y), fmaxf(v.z, v.w)));
    }
    bool valid = m > 0.5f;
    g_key[i] = valid ? score : -1.0f;
    float px = loc[2 * i], py = loc[2 * i + 1];
    float4 b;
    b.x = __fmul_rn(tb[0], px);
    b.y = __fmul_rn(tb[1], py);
    b.z = __fmul_rn(tb[2], px);
    b.w = __fmul_rn(tb[3], py);
    g_boxes[i] = b;
}

// ---------------- K2: counting sort rank + filtered index ----------------
// rank_i = #{valid j : key_j > key_i || (key_j == key_i && j < i)}  (stable desc sort)
// fic_i  = #{valid j : j < i}
__global__ void k_rank(void) {
    __shared__ float skey[256];
    int j0 = blockIdx.y * 256;
    skey[threadIdx.x] = g_key[j0 + threadIdx.x];
    __syncthreads();
    int i = blockIdx.x * 256 + threadIdx.x;
    float ki = g_key[i];
    int r = 0, f = 0;
    #pragma unroll 8
    for (int jj = 0; jj < 256; ++jj) {
        float kj = skey[jj];
        int j = j0 + jj;
        bool valid_j = kj >= 0.0f;
        r += (kj > ki) || (kj == ki && j < i && valid_j);
        f += (j < i) && valid_j;
    }
    atomicAdd(&g_rank[i], r);
    atomicAdd(&g_fic[i], f);
}

// ---------------- K3: scatter into sorted order (+ count F here) ----------------
__global__ void k_scatter(void) {
    int i = blockIdx.x * 256 + threadIdx.x;
    if (i >= N_ANCHORS) return;
    if (g_key[i] >= 0.0f) {
        int p = g_rank[i];
        g_sAnchor[p] = i;
        g_sFi[p] = g_fic[i];
        g_sbox[p] = g_boxes[i];
        atomicAdd(&g_F, 1);
    }
}

// ---------------- K4: IoU > 0.5 bitmask, upper triangle (word >= row/64) ----------------
// NOTE: the __fdiv_rn must stay — predicate must be bit-identical to XLA's
// inter/union division; a mul-compare rewrite flips ~2 expected borderline
// pairs out of 18.9M (q in (0.5, 0.5*(1+2^-24)]) and changes the kept set.
__global__ void __launch_bounds__(256) k_mask(void) {
    int wave = (blockIdx.x * 256 + threadIdx.x) >> 6;
    int lane = threadIdx.x & 63;
    if (wave >= N_ANCHORS) return;
    int i = wave;
    float4 bi = g_sbox[i];
    float areai = __fmul_rn(bi.z - bi.x, bi.w - bi.y);
    unsigned long long* row = g_mask + (size_t)i * NWORDS;
    for (int w = (i >> 6); w < NWORDS; ++w) {
        float4 bj = g_sbox[w * 64 + lane];
        float areaj = __fmul_rn(bj.z - bj.x, bj.w - bj.y);
        float lx = fmaxf(bi.x, bj.x), ly = fmaxf(bi.y, bj.y);
        float rx = fminf(bi.z, bj.z), ry = fminf(bi.w, bj.w);
        float iw = fmaxf(rx - lx, 0.0f), ih = fmaxf(ry - ly, 0.0f);
        float inter = __fmul_rn(iw, ih);
        float denom = __fsub_rn(__fadd_rn(areai, areaj), inter);
        float iou = __fdiv_rn(inter, denom);
        unsigned long long bits = __ballot(iou > 0.5f);
        if (lane == 0) row[w] = bits;
    }
}

// ---------------- K5: single-wave greedy-NMS scan (batch = 16 candidate rows) ----------------
__global__ void __launch_bounds__(64) k_scan(void) {
    int lane = threadIdx.x;
    int F = g_F;
    // remv word init: positions >= F pre-suppressed
    auto initw = [&](int w) -> unsigned long long {
        long long lo = (long long)w * 64, hi = lo + 64;
        if (F <= lo) return ~0ull;
        if (F >= hi) return 0ull;
        return (~0ull) << (F - lo);
    };
    unsigned long long remv0 = initw(lane);                                  // word lane
    unsigned long long remv1 = (lane < 32) ? initw(64 + lane) : ~0ull;       // word 64+lane
    unsigned long long kept0 = 0, kept1 = 0;

    #define SCAN_BATCH 16
    for (int w = 0; w < NWORDS; ++w) {
        unsigned long long cur = (w < 64) ? shfl64(remv0, w) : shfl64(remv1, w - 64);
        unsigned long long cand = ~cur;
        while (cand) {
            // extract up to SCAN_BATCH candidate bit positions (wave-uniform)
            unsigned long long tmp = cand;
            int pos[SCAN_BATCH];
            #pragma unroll
            for (int q = 0; q < SCAN_BATCH; ++q) {
                pos[q] = tmp ? __builtin_ctzll(tmp) : 64;
                tmp &= tmp - 1;
            }
            // batch-load full mask rows of all candidates (96 words over 64 lanes)
            // -> one L3 round-trip amortized over up to 16 candidates
            unsigned long long r0[SCAN_BATCH], r1[SCAN_BATCH];
            #pragma unroll
            for (int q = 0; q < SCAN_BATCH; ++q) {
                if (pos[q] < 64) {
                    const unsigned long long* rp = g_mask + (size_t)(w * 64 + pos[q]) * NWORDS;
                    r0[q] = rp[lane];
                    r1[q] = (lane < 32) ? rp[64 + lane] : 0ull;
                } else { r0[q] = 0ull; r1[q] = 0ull; }
            }
            // resolve greedy order inside this word (all values wave-uniform)
            unsigned long long m = cur, keptloc = 0, batch = 0;
            #pragma unroll
            for (int q = 0; q < SCAN_BATCH; ++q) {
                if (pos[q] < 64) {
                    batch |= 1ull << pos[q];
                    if (!((m >> pos[q]) & 1ull)) {
                        keptloc |= 1ull << pos[q];
                        unsigned long long iw = (w < 64) ? shfl64(r0[q], w) : shfl64(r1[q], w - 64);
                        m |= iw;  // kept candidate suppresses later bits of this word
                    }
                }
            }
            // fold kept candidates' rows into the global suppression mask
            #pragma unroll
            for (int q = 0; q < SCAN_BATCH; ++q)
                if ((pos[q] < 64) && ((keptloc >> pos[q]) & 1ull)) { remv0 |= r0[q]; remv1 |= r1[q]; }
            if (w < 64) { if (lane == w) kept0 |= keptloc; }
            else        { if (lane == w - 64) kept1 |= keptloc; }
            cur = m;
            cand = cand & ~batch & ~m;
        }
    }

    // compact kept list in sorted order
    int c0 = __popcll(kept0);
    int c1 = (lane < 32) ? __popcll(kept1) : 0;
    int x0 = c0, x1 = c1;
    for (int ofs = 1; ofs < 64; ofs <<= 1) {
        int y0 = __shfl_up(x0, ofs, 64);
        int y1 = __shfl_up(x1, ofs, 64);
        if (lane >= ofs) { x0 += y0; x1 += y1; }
    }
    int t0 = __shfl(x0, 63, 64);
    int t1 = __shfl(x1, 63, 64);
    int off = x0 - c0;
    unsigned long long wd = kept0;
    while (wd) { int b = __builtin_ctzll(wd); g_keptPos[off++] = lane * 64 + b; wd &= wd - 1; }
    off = t0 + (x1 - c1);
    wd = kept1;
    while (wd) { int b = __builtin_ctzll(wd); g_keptPos[off++] = (64 + lane) * 64 + b; wd &= wd - 1; }
    if (lane == 0) g_K = t0 + t1;
}

// ---------------- K6: per-class top-1 (ties -> first kept) + smooth-L1 + num_pos
//                      + fused finalize via last-block-done counter ----------------
// Cross-block/XCD traffic all via device-scope atomics at the coherent point
// (per-XCD L2s are not coherent; plain stores would be unsafe here).
__global__ void __launch_bounds__(64) k_loss(const float* __restrict__ conf, const float* __restrict__ tb,
                                             float* __restrict__ out) {
    int c = blockIdx.x;
    int lane = threadIdx.x;
    int K = g_K;
    float bv = -3.402823466e+38f;
    int bk = 0x7fffffff;
    int np = 0;
    for (int k = lane; k < K; k += 64) {
        int p = g_keptPos[k];
        int a = g_sAnchor[p];
        float v = conf[(size_t)a * NUM_CLASSES + c];
        if (v > bv || (v == bv && k < bk)) { bv = v; bk = k; }
        if (c == 0) np += g_sFi[p];
    }
    for (int ofs = 32; ofs > 0; ofs >>= 1) {
        float ov = __shfl_down(bv, ofs, 64);
        int ok = __shfl_down(bk, ofs, 64);
        if (ov > bv || (ov == bv && ok < bk)) { bv = ov; bk = ok; }
    }
    if (c == 0) {
        for (int ofs = 32; ofs > 0; ofs >>= 1) np += __shfl_down(np, ofs, 64);
        if (lane == 0) atomicExch(&g_np, np);   // device-scope write (cross-XCD reader)
    }
    if (lane == 0) {
        if (K > 0) {
            float4 b = g_sbox[g_keptPos[bk]];
            float t0 = tb[0], t1 = tb[1], t2 = tb[2], t3 = tb[3];
            float l = 0.0f, d;
            d = fabsf(b.x - t0); l += (d < 1.0f) ? 0.5f * d * d : d - 0.5f;
            d = fabsf(b.y - t1); l += (d < 1.0f) ? 0.5f * d * d : d - 0.5f;
            d = fabsf(b.z - t2); l += (d < 1.0f) ? 0.5f * d * d : d - 0.5f;
            d = fabsf(b.w - t3); l += (d < 1.0f) ? 0.5f * d * d : d - 0.5f;
            atomicAdd(&g_loss, l);
        }
        __threadfence();                          // order my atomics before the done-count
        int done = atomicAdd(&g_done, 1);
        if (done == NUM_CLASSES - 1) {            // last block finalizes (saves a launch)
            float total = atomicAdd(&g_loss, 0.0f);   // coherent-point read
            int npv = atomicAdd(&g_np, 0);            // coherent-point read
            out[0] = (g_F == 0 || K == 0) ? 0.001f : total / (float)npv;
        }
    }
}

extern "C" void kernel_launch(void* const* d_in, const int* in_sizes, int n_in,
                              void* d_out, int out_size, void* d_ws, size_t ws_size,
                              hipStream_t stream) {
    const float* loc  = (const float*)d_in[0];   // (1, 6144, 2)  f32
    const float* conf = (const float*)d_in[1];   // (1, 6144, 80) f32
    const float* tb   = (const float*)d_in[2];   // (1, 1, 4)     f32
    float* out = (float*)d_out;

    k_prep<<<24, 256, 0, stream>>>(loc, conf, tb);
    k_rank<<<dim3(24, 24), 256, 0, stream>>>();
    k_scatter<<<24, 256, 0, stream>>>();
    k_mask<<<(N_ANCHORS * 64) / 256, 256, 0, stream>>>();
    k_scan<<<1, 64, 0, stream>>>();
    k_loss<<<NUM_CLASSES, 64, 0, stream>>>(conf, tb, out);
}

// Round 2
// 159.080 us; speedup vs baseline: 1.3307x; 1.3307x over previous
//
#include <hip/hip_runtime.h>
#include <stdint.h>

#define N_ANCHORS 6144
#define NUM_CLASSES 80
#define NWORDS 96   // 6144 / 64

// ---------------- static device scratch (avoids ws_size assumptions) ----------------
__device__ unsigned long long g_mask[(size_t)N_ANCHORS * NWORDS]; // suppression bitmask rows (sorted space)
__device__ float4 g_boxes[N_ANCHORS];    // per-anchor box
__device__ float4 g_sbox[N_ANCHORS];     // sorted boxes
__device__ float  g_key[N_ANCHORS];      // score if valid else -1
__device__ int    g_rank[N_ANCHORS];     // sorted position of valid anchor
__device__ int    g_fic[N_ANCHORS];      // filtered index of valid anchor
__device__ int    g_sAnchor[N_ANCHORS];  // sorted pos -> anchor id
__device__ int    g_sFi[N_ANCHORS];      // sorted pos -> filtered index
__device__ int    g_keptPos[N_ANCHORS];  // compact kept list (sorted positions, ascending)
__device__ int    g_F, g_K, g_np, g_done;
__device__ float  g_loss;

__device__ __forceinline__ unsigned long long shfl64(unsigned long long v, int l) {
    return __shfl(v, l, 64);
}

// ---------------- K1: per-anchor prep (fused zeroing; g_F counted in k_scatter to
// avoid zero/accumulate race within this kernel) ----------------
__global__ void k_prep(const float* __restrict__ loc, const float* __restrict__ conf,
                       const float* __restrict__ tb) {
    int i = blockIdx.x * 256 + threadIdx.x;
    if (i >= N_ANCHORS) return;
    g_rank[i] = 0; g_fic[i] = 0;
    if (i == 0) { g_F = 0; g_K = 0; g_np = 0; g_loss = 0.0f; g_done = 0; }
    const float4* cp4 = (const float4*)(conf + (size_t)i * NUM_CLASSES);
    float4 v0 = cp4[0];
    float score = v0.x;
    float m = fmaxf(fmaxf(v0.x, v0.y), fmaxf(v0.z, v0.w));
    #pragma unroll
    for (int c = 1; c < NUM_CLASSES / 4; ++c) {
        float4 v = cp4[c];
        m = fmaxf(m, fmaxf(fmaxf(v.x, v.y), fmaxf(v.z, v.w)));
    }
    bool valid = m > 0.5f;
    g_key[i] = valid ? score : -1.0f;
    float px = loc[2 * i], py = loc[2 * i + 1];
    float4 b;
    b.x = __fmul_rn(tb[0], px);
    b.y = __fmul_rn(tb[1], py);
    b.z = __fmul_rn(tb[2], px);
    b.w = __fmul_rn(tb[3], py);
    g_boxes[i] = b;
}

// ---------------- K2: counting sort rank + filtered index ----------------
// rank_i = #{valid j : key_j > key_i || (key_j == key_i && j < i)}  (stable desc sort)
// fic_i  = #{valid j : j < i}
__global__ void k_rank(void) {
    __shared__ float skey[256];
    int j0 = blockIdx.y * 256;
    skey[threadIdx.x] = g_key[j0 + threadIdx.x];
    __syncthreads();
    int i = blockIdx.x * 256 + threadIdx.x;
    float ki = g_key[i];
    int r = 0, f = 0;
    #pragma unroll 8
    for (int jj = 0; jj < 256; ++jj) {
        float kj = skey[jj];
        int j = j0 + jj;
        bool valid_j = kj >= 0.0f;
        r += (kj > ki) || (kj == ki && j < i && valid_j);
        f += (j < i) && valid_j;
    }
    atomicAdd(&g_rank[i], r);
    atomicAdd(&g_fic[i], f);
}

// ---------------- K3: scatter into sorted order (+ count F here) ----------------
__global__ void k_scatter(void) {
    int i = blockIdx.x * 256 + threadIdx.x;
    if (i >= N_ANCHORS) return;
    if (g_key[i] >= 0.0f) {
        int p = g_rank[i];
        g_sAnchor[p] = i;
        g_sFi[p] = g_fic[i];
        g_sbox[p] = g_boxes[i];
        atomicAdd(&g_F, 1);
    }
}

// ---------------- K4: IoU > 0.5 bitmask, upper triangle (word >= row/64) ----------------
// NOTE: the __fdiv_rn must stay — predicate must be bit-identical to XLA's
// inter/union division; a mul-compare rewrite flips ~2 expected borderline
// pairs out of 18.9M (q in (0.5, 0.5*(1+2^-24)]) and changes the kept set.
__global__ void __launch_bounds__(256) k_mask(void) {
    int wave = (blockIdx.x * 256 + threadIdx.x) >> 6;
    int lane = threadIdx.x & 63;
    if (wave >= N_ANCHORS) return;
    int i = wave;
    float4 bi = g_sbox[i];
    float areai = __fmul_rn(bi.z - bi.x, bi.w - bi.y);
    unsigned long long* row = g_mask + (size_t)i * NWORDS;
    for (int w = (i >> 6); w < NWORDS; ++w) {
        float4 bj = g_sbox[w * 64 + lane];
        float areaj = __fmul_rn(bj.z - bj.x, bj.w - bj.y);
        float lx = fmaxf(bi.x, bj.x), ly = fmaxf(bi.y, bj.y);
        float rx = fminf(bi.z, bj.z), ry = fminf(bi.w, bj.w);
        float iw = fmaxf(rx - lx, 0.0f), ih = fmaxf(ry - ly, 0.0f);
        float inter = __fmul_rn(iw, ih);
        float denom = __fsub_rn(__fadd_rn(areai, areaj), inter);
        float iou = __fdiv_rn(inter, denom);
        unsigned long long bits = __ballot(iou > 0.5f);
        if (lane == 0) row[w] = bits;
    }
}

// ---------------- K5: single-wave greedy-NMS scan, GLOBAL candidate batching ----------------
// Key insight (rocprof r1): suppression only shrinks the candidate set, so the first
// B unsuppressed positions under the CURRENT remv are a sound superset of the next B
// greedy decisions. Batch-load their mask rows in ONE round trip (vs per-word batching
// which degenerated to ~94 sequential L3 round trips = 99 us).
#define SCAN_B 16
__global__ void __launch_bounds__(64) k_scan(void) {
    int lane = threadIdx.x;
    int F = g_F;
    // remv word init: positions >= F pre-suppressed
    auto initw = [&](int w) -> unsigned long long {
        long long lo = (long long)w * 64, hi = lo + 64;
        if (F <= lo) return ~0ull;
        if (F >= hi) return 0ull;
        return (~0ull) << (F - lo);
    };
    unsigned long long remv0 = initw(lane);                                  // word lane
    unsigned long long remv1 = (lane < 32) ? initw(64 + lane) : ~0ull;       // word 64+lane
    unsigned long long kept0 = 0, kept1 = 0;
    int lastPos = -1;   // greedy decisions finalized for all positions <= lastPos

    __shared__ int slots[SCAN_B];

    while (true) {
        // --- extract first SCAN_B candidate positions > lastPos under current remv ---
        unsigned long long c0 = ~remv0;                       // word = lane
        unsigned long long c1 = (lane < 32) ? ~remv1 : 0ull;  // word = 64 + lane
        {
            long long lo = (long long)lane << 6;
            if (lastPos >= lo + 63)      c0 = 0ull;
            else if (lastPos >= lo)      c0 &= (~0ull) << (int)(lastPos - lo + 1);
        }
        if (lane < 32) {
            long long lo = (long long)(64 + lane) << 6;
            if (lastPos >= lo + 63)      c1 = 0ull;
            else if (lastPos >= lo)      c1 &= (~0ull) << (int)(lastPos - lo + 1);
        }
        int n0 = __popcll(c0), n1 = __popcll(c1);
        int x0 = n0, x1 = n1;
        for (int ofs = 1; ofs < 64; ofs <<= 1) {
            int y0 = __shfl_up(x0, ofs, 64);
            int y1 = __shfl_up(x1, ofs, 64);
            if (lane >= ofs) { x0 += y0; x1 += y1; }
        }
        int tot0 = __shfl(x0, 63, 64);
        int tot1 = __shfl(x1, 63, 64);     // n1 == 0 for lane >= 32, so lane63 holds full sum
        int total = tot0 + tot1;
        if (total == 0) break;
        int off0 = x0 - n0;
        int off1 = tot0 + (x1 - n1);
        {   // write the first SCAN_B candidate positions (global rank order) to LDS
            unsigned long long wd = c0; int r = off0;
            while (wd && r < SCAN_B) { int b = __builtin_ctzll(wd); slots[r++] = lane * 64 + b; wd &= wd - 1; }
        }
        if (lane < 32) {
            unsigned long long wd = c1; int r = off1;
            while (wd && r < SCAN_B) { int b = __builtin_ctzll(wd); slots[r++] = (64 + lane) * 64 + b; wd &= wd - 1; }
        }
        __syncthreads();   // lgkmcnt drain: LDS writes visible before uniform reads
        int nb = (total < SCAN_B) ? total : SCAN_B;
        int pos[SCAN_B];
        #pragma unroll
        for (int q = 0; q < SCAN_B; ++q) pos[q] = (q < nb) ? slots[q] : -1;
        __syncthreads();   // all lanes past the reads before next-iter writes

        // --- one fused round trip: load all candidate rows (96 words over 64 lanes) ---
        unsigned long long r0[SCAN_B], r1[SCAN_B];
        #pragma unroll
        for (int q = 0; q < SCAN_B; ++q) {
            if (pos[q] >= 0) {
                const unsigned long long* rp = g_mask + (size_t)pos[q] * NWORDS;
                r0[q] = rp[lane];
                r1[q] = (lane < 32) ? rp[64 + lane] : 0ull;
            } else { r0[q] = 0ull; r1[q] = 0ull; }
        }

        // --- sequential greedy resolve (wave-uniform decisions, ~40 cy/candidate) ---
        #pragma unroll
        for (int q = 0; q < SCAN_B; ++q) {
            if (pos[q] >= 0) {
                int w = pos[q] >> 6, b = pos[q] & 63;
                unsigned long long cw = (w < 64) ? shfl64(remv0, w) : shfl64(remv1, w - 64);
                if (!((cw >> b) & 1ull)) {
                    // kept: fold its row into the distributed suppression state
                    remv0 |= r0[q];
                    if (lane < 32) remv1 |= r1[q];
                    if (w < 64) { if (lane == w) kept0 |= 1ull << b; }
                    else        { if (lane == w - 64) kept1 |= 1ull << b; }
                }
                lastPos = pos[q];
            }
        }
    }

    // compact kept list in sorted order
    int c0 = __popcll(kept0);
    int c1 = (lane < 32) ? __popcll(kept1) : 0;
    int x0 = c0, x1 = c1;
    for (int ofs = 1; ofs < 64; ofs <<= 1) {
        int y0 = __shfl_up(x0, ofs, 64);
        int y1 = __shfl_up(x1, ofs, 64);
        if (lane >= ofs) { x0 += y0; x1 += y1; }
    }
    int t0 = __shfl(x0, 63, 64);
    int t1 = __shfl(x1, 63, 64);
    int off = x0 - c0;
    unsigned long long wd = kept0;
    while (wd) { int b = __builtin_ctzll(wd); g_keptPos[off++] = lane * 64 + b; wd &= wd - 1; }
    off = t0 + (x1 - c1);
    wd = kept1;
    while (wd) { int b = __builtin_ctzll(wd); g_keptPos[off++] = (64 + lane) * 64 + b; wd &= wd - 1; }
    if (lane == 0) g_K = t0 + t1;
}

// ---------------- K6: per-class top-1 (ties -> first kept) + smooth-L1 + num_pos
//                      + fused finalize via last-block-done counter ----------------
// Cross-block/XCD traffic all via device-scope atomics at the coherent point
// (per-XCD L2s are not coherent; plain stores would be unsafe here).
__global__ void __launch_bounds__(64) k_loss(const float* __restrict__ conf, const float* __restrict__ tb,
                                             float* __restrict__ out) {
    int c = blockIdx.x;
    int lane = threadIdx.x;
    int K = g_K;
    float bv = -3.402823466e+38f;
    int bk = 0x7fffffff;
    int np = 0;
    for (int k = lane; k < K; k += 64) {
        int p = g_keptPos[k];
        int a = g_sAnchor[p];
        float v = conf[(size_t)a * NUM_CLASSES + c];
        if (v > bv || (v == bv && k < bk)) { bv = v; bk = k; }
        if (c == 0) np += g_sFi[p];
    }
    for (int ofs = 32; ofs > 0; ofs >>= 1) {
        float ov = __shfl_down(bv, ofs, 64);
        int ok = __shfl_down(bk, ofs, 64);
        if (ov > bv || (ov == bv && ok < bk)) { bv = ov; bk = ok; }
    }
    if (c == 0) {
        for (int ofs = 32; ofs > 0; ofs >>= 1) np += __shfl_down(np, ofs, 64);
        if (lane == 0) atomicExch(&g_np, np);   // device-scope write (cross-XCD reader)
    }
    if (lane == 0) {
        if (K > 0) {
            float4 b = g_sbox[g_keptPos[bk]];
            float t0 = tb[0], t1 = tb[1], t2 = tb[2], t3 = tb[3];
            float l = 0.0f, d;
            d = fabsf(b.x - t0); l += (d < 1.0f) ? 0.5f * d * d : d - 0.5f;
            d = fabsf(b.y - t1); l += (d < 1.0f) ? 0.5f * d * d : d - 0.5f;
            d = fabsf(b.z - t2); l += (d < 1.0f) ? 0.5f * d * d : d - 0.5f;
            d = fabsf(b.w - t3); l += (d < 1.0f) ? 0.5f * d * d : d - 0.5f;
            atomicAdd(&g_loss, l);
        }
        __threadfence();                          // order my atomics before the done-count
        int done = atomicAdd(&g_done, 1);
        if (done == NUM_CLASSES - 1) {            // last block finalizes (saves a launch)
            float total = atomicAdd(&g_loss, 0.0f);   // coherent-point read
            int npv = atomicAdd(&g_np, 0);            // coherent-point read
            out[0] = (g_F == 0 || K == 0) ? 0.001f : total / (float)npv;
        }
    }
}

extern "C" void kernel_launch(void* const* d_in, const int* in_sizes, int n_in,
                              void* d_out, int out_size, void* d_ws, size_t ws_size,
                              hipStream_t stream) {
    const float* loc  = (const float*)d_in[0];   // (1, 6144, 2)  f32
    const float* conf = (const float*)d_in[1];   // (1, 6144, 80) f32
    const float* tb   = (const float*)d_in[2];   // (1, 1, 4)     f32
    float* out = (float*)d_out;

    k_prep<<<24, 256, 0, stream>>>(loc, conf, tb);
    k_rank<<<dim3(24, 24), 256, 0, stream>>>();
    k_scatter<<<24, 256, 0, stream>>>();
    k_mask<<<(N_ANCHORS * 64) / 256, 256, 0, stream>>>();
    k_scan<<<1, 64, 0, stream>>>();
    k_loss<<<NUM_CLASSES, 64, 0, stream>>>(conf, tb, out);
}